// Round 2
// baseline (918.158 us; speedup 1.0000x reference)
//
#include <hip/hip_runtime.h>
#include <hip/hip_bf16.h>

#define NN 100000
#define NE 1600000
#define D  128
#define DOUT 64
#define NORM_SCALE 1.0f

// ---------------- CSR build ----------------

__global__ void hist_kernel(const int* __restrict__ dst, int* __restrict__ counts) {
    int e = blockIdx.x * 256 + threadIdx.x;
    if (e < NE) atomicAdd(&counts[dst[e]], 1);
}

__global__ void scan_partial_kernel(const int* __restrict__ counts, int* __restrict__ partial) {
    __shared__ int s[256];
    int t = threadIdx.x;
    int i = blockIdx.x * 256 + t;
    s[t] = (i < NN) ? counts[i] : 0;
    __syncthreads();
    for (int off = 128; off; off >>= 1) {
        if (t < off) s[t] += s[t + off];
        __syncthreads();
    }
    if (t == 0) partial[blockIdx.x] = s[0];
}

__global__ void scan_block_kernel(int* __restrict__ partial, int nblk) {
    __shared__ int s[512];
    int t = threadIdx.x;
    s[t] = (t < nblk) ? partial[t] : 0;
    __syncthreads();
    for (int off = 1; off < 512; off <<= 1) {
        int v = (t >= off) ? s[t - off] : 0;
        __syncthreads();
        s[t] += v;
        __syncthreads();
    }
    // exclusive
    if (t < nblk) partial[t] = (t == 0) ? 0 : s[t - 1];
}

__global__ void scan_final_kernel(const int* __restrict__ counts, const int* __restrict__ partial,
                                  int* __restrict__ row_start, int* __restrict__ cursor) {
    __shared__ int s[256];
    int t = threadIdx.x;
    int i = blockIdx.x * 256 + t;
    int v = (i < NN) ? counts[i] : 0;
    s[t] = v;
    __syncthreads();
    for (int off = 1; off < 256; off <<= 1) {
        int u = (t >= off) ? s[t - off] : 0;
        __syncthreads();
        s[t] += u;
        __syncthreads();
    }
    int excl = s[t] - v;
    int rs = partial[blockIdx.x] + excl;
    if (i < NN) { row_start[i] = rs; cursor[i] = rs; }
    if (i == 0) row_start[NN] = NE;
}

__global__ void scatter_kernel(const int* __restrict__ src, const int* __restrict__ dst,
                               int* __restrict__ cursor, int* __restrict__ src_sorted) {
    int e = blockIdx.x * 256 + threadIdx.x;
    if (e < NE) {
        int p = atomicAdd(&cursor[dst[e]], 1);
        src_sorted[p] = src[e];
    }
}

// ---------------- mean aggregation: one wave per node ----------------

__global__ void agg_mean_kernel(const float* __restrict__ feat,
                                const int* __restrict__ row_start,
                                const int* __restrict__ src_sorted,
                                float* __restrict__ out) {
    int node = blockIdx.x * 4 + (threadIdx.x >> 6);
    int lane = threadIdx.x & 63;
    if (node >= NN) return;
    int s = row_start[node];
    int e = row_start[node + 1];
    float2 acc = make_float2(0.f, 0.f);
    for (int p = s; p < e; ++p) {
        int src = src_sorted[p];
        float2 v = *(const float2*)&feat[(size_t)src * D + 2 * lane];
        acc.x += v.x; acc.y += v.y;
    }
    float inv = 1.0f / (float)((e - s) > 1 ? (e - s) : 1);
    float2 r = make_float2(acc.x * inv, acc.y * inv);
    *(float2*)&out[(size_t)node * D + 2 * lane] = r;
}

// ---------------- layer1 linear: h_pre = mean1@Wl1 + bl1 + x@Wr1 ----------------
// also per-row sum of squares -> rn[node], and per-column partial sums -> 64 replicated copies

__global__ void linear1_kernel(const float* __restrict__ x, const float* __restrict__ mean1,
                               const float* __restrict__ Wl, const float* __restrict__ bl,
                               const float* __restrict__ Wr,
                               float* __restrict__ hpre, float* __restrict__ rn,
                               float* __restrict__ cscopies) {
    __shared__ float sx[16][D];
    __shared__ float sm[16][D];
    __shared__ float cp[4][D];
    int tid = threadIdx.x;
    int nb = blockIdx.x * 16;
    for (int i = tid; i < 16 * D; i += 256) {
        int n = i >> 7, c = i & 127;
        sx[n][c] = x[(size_t)(nb + n) * D + c];
        sm[n][c] = mean1[(size_t)(nb + n) * D + c];
    }
    __syncthreads();
    int w = tid >> 6, l = tid & 63;
    float acc[4][2];
#pragma unroll
    for (int i = 0; i < 4; ++i) { acc[i][0] = bl[l]; acc[i][1] = bl[l + 64]; }
    for (int k = 0; k < D; ++k) {
        float wl0 = Wl[k * D + l];
        float wl1 = Wl[k * D + l + 64];
        float wr0 = Wr[k * D + l];
        float wr1 = Wr[k * D + l + 64];
#pragma unroll
        for (int i = 0; i < 4; ++i) {
            int n = w * 4 + i;
            float m = sm[n][k];
            float xx = sx[n][k];
            acc[i][0] += m * wl0 + xx * wr0;
            acc[i][1] += m * wl1 + xx * wr1;
        }
    }
    float c0 = 0.f, c1 = 0.f;
#pragma unroll
    for (int i = 0; i < 4; ++i) {
        int node = nb + w * 4 + i;
        hpre[(size_t)node * D + l] = acc[i][0];
        hpre[(size_t)node * D + l + 64] = acc[i][1];
        float si = acc[i][0] * acc[i][0] + acc[i][1] * acc[i][1];
#pragma unroll
        for (int off = 32; off; off >>= 1) si += __shfl_xor(si, off, 64);
        if (l == 0) rn[node] = sqrtf(1e-6f + si);
        c0 += acc[i][0]; c1 += acc[i][1];
    }
    cp[w][l] = c0; cp[w][l + 64] = c1;
    __syncthreads();
    if (tid < D) {
        float s = cp[0][tid] + cp[1][tid] + cp[2][tid] + cp[3][tid];
        atomicAdd(&cscopies[(blockIdx.x & 63) * D + tid], s);
    }
}

__global__ void colreduce_kernel(const float* __restrict__ cscopies, float* __restrict__ colmean) {
    int c = threadIdx.x;
    if (c < D) {
        float s = 0.f;
        for (int j = 0; j < 64; ++j) s += cscopies[j * D + c];
        colmean[c] = s * (1.0f / (float)NN);
    }
}

// ---------------- pairnorm-scs + relu, in place ----------------

__global__ void pairnorm_relu_kernel(float* __restrict__ h, const float* __restrict__ rn,
                                     const float* __restrict__ colmean) {
    int idx = blockIdx.x * 256 + threadIdx.x;        // one float4 per thread
    const int total = NN * D / 4;
    if (idx >= total) return;
    int n = idx >> 5;          // 32 float4 per row
    int c4 = idx & 31;
    float4 v = ((float4*)h)[idx];
    float riv = NORM_SCALE / rn[n];
    float4 cm = ((const float4*)colmean)[c4];
    v.x = fmaxf(v.x * riv - cm.x, 0.f);
    v.y = fmaxf(v.y * riv - cm.y, 0.f);
    v.z = fmaxf(v.z * riv - cm.z, 0.f);
    v.w = fmaxf(v.w * riv - cm.w, 0.f);
    ((float4*)h)[idx] = v;
}

// ---------------- layer2 linear: out = mean2@Wl2 + bl2 + h@Wr2 ----------------

__global__ void linear2_kernel(const float* __restrict__ h, const float* __restrict__ mean2,
                               const float* __restrict__ Wl, const float* __restrict__ bl,
                               const float* __restrict__ Wr, float* __restrict__ out) {
    __shared__ float sx[16][D];
    __shared__ float sm[16][D];
    int tid = threadIdx.x;
    int nb = blockIdx.x * 16;
    for (int i = tid; i < 16 * D; i += 256) {
        int n = i >> 7, c = i & 127;
        sx[n][c] = h[(size_t)(nb + n) * D + c];
        sm[n][c] = mean2[(size_t)(nb + n) * D + c];
    }
    __syncthreads();
    int w = tid >> 6, l = tid & 63;   // l in [0,64) == output col
    float acc[4];
#pragma unroll
    for (int i = 0; i < 4; ++i) acc[i] = bl[l];
    for (int k = 0; k < D; ++k) {
        float wl = Wl[k * DOUT + l];
        float wr = Wr[k * DOUT + l];
#pragma unroll
        for (int i = 0; i < 4; ++i) {
            int n = w * 4 + i;
            acc[i] += sm[n][k] * wl + sx[n][k] * wr;
        }
    }
#pragma unroll
    for (int i = 0; i < 4; ++i) {
        int node = nb + w * 4 + i;
        out[(size_t)node * DOUT + l] = acc[i];
    }
}

// ---------------- launch ----------------

extern "C" void kernel_launch(void* const* d_in, const int* in_sizes, int n_in,
                              void* d_out, int out_size, void* d_ws, size_t ws_size,
                              hipStream_t stream) {
    const float* x   = (const float*)d_in[0];
    const int*   ei  = (const int*)d_in[1];     // [2][NE] int32
    const float* Wl1 = (const float*)d_in[2];
    const float* bl1 = (const float*)d_in[3];
    const float* Wr1 = (const float*)d_in[4];
    const float* Wl2 = (const float*)d_in[5];
    const float* bl2 = (const float*)d_in[6];
    const float* Wr2 = (const float*)d_in[7];
    const int* src = ei;
    const int* dst = ei + NE;
    float* out = (float*)d_out;

    // bump allocator over workspace (256B aligned regions)
    char* p = (char*)d_ws;
    auto alloc = [&](size_t bytes) -> void* {
        void* r = (void*)p;
        p += (bytes + 255) & ~(size_t)255;
        return r;
    };
    int* counts     = (int*)alloc((size_t)NN * 4);
    int* cursor     = (int*)alloc((size_t)NN * 4);
    int* row_start  = (int*)alloc((size_t)(NN + 1) * 4);
    int* partial    = (int*)alloc(512 * 4);
    int* src_sorted = (int*)alloc((size_t)NE * 4);
    float* mean1    = (float*)alloc((size_t)NN * D * 4);   // reused as mean2
    float* hbuf     = (float*)alloc((size_t)NN * D * 4);
    float* rn       = (float*)alloc((size_t)NN * 4);
    float* cscopies = (float*)alloc(64 * D * 4);
    float* colmean  = (float*)alloc(D * 4);

    const int NBLK_SCAN = (NN + 255) / 256;    // 391
    const int NBLK_E    = (NE + 255) / 256;    // 6250
    const int NBLK_AGG  = (NN + 3) / 4;        // 25000
    const int NBLK_LIN  = NN / 16;             // 6250 (100000 % 16 == 0)
    const int NBLK_PN   = (NN * D / 4 + 255) / 256;  // 12500

    hipMemsetAsync(counts, 0, (size_t)NN * 4, stream);
    hipMemsetAsync(cscopies, 0, 64 * D * 4, stream);

    // CSR build (shared by both layers)
    hist_kernel<<<NBLK_E, 256, 0, stream>>>(dst, counts);
    scan_partial_kernel<<<NBLK_SCAN, 256, 0, stream>>>(counts, partial);
    scan_block_kernel<<<1, 512, 0, stream>>>(partial, NBLK_SCAN);
    scan_final_kernel<<<NBLK_SCAN, 256, 0, stream>>>(counts, partial, row_start, cursor);
    scatter_kernel<<<NBLK_E, 256, 0, stream>>>(src, dst, cursor, src_sorted);

    // layer 1
    agg_mean_kernel<<<NBLK_AGG, 256, 0, stream>>>(x, row_start, src_sorted, mean1);
    linear1_kernel<<<NBLK_LIN, 256, 0, stream>>>(x, mean1, Wl1, bl1, Wr1, hbuf, rn, cscopies);
    colreduce_kernel<<<1, 128, 0, stream>>>(cscopies, colmean);
    pairnorm_relu_kernel<<<NBLK_PN, 256, 0, stream>>>(hbuf, rn, colmean);

    // layer 2
    agg_mean_kernel<<<NBLK_AGG, 256, 0, stream>>>(hbuf, row_start, src_sorted, mean1);
    linear2_kernel<<<NBLK_LIN, 256, 0, stream>>>(hbuf, mean1, Wl2, bl2, Wr2, out);
}

// Round 3
// 546.177 us; speedup vs baseline: 1.6811x; 1.6811x over previous
//
#include <hip/hip_runtime.h>

#define NN 100000
#define NE 1600000
#define D  128
#define DOUT 64
#define K2 256
#define NORM_SCALE 1.0f

using short8 = __attribute__((ext_vector_type(8))) short;
using f32x4  = __attribute__((ext_vector_type(4))) float;

__device__ inline unsigned short f2bf(float f) {
    union { float f; unsigned int u; } v; v.f = f;
    unsigned int r = v.u + 0x7FFFu + ((v.u >> 16) & 1u);
    return (unsigned short)(r >> 16);
}
__device__ inline float bf2f(unsigned short u) {
    union { unsigned int u; float f; } v; v.u = ((unsigned int)u) << 16;
    return v.f;
}

// ---------------- CSR build ----------------

__global__ void hist_kernel(const int* __restrict__ dst, int* __restrict__ counts) {
    int e = blockIdx.x * 256 + threadIdx.x;
    if (e < NE) atomicAdd(&counts[dst[e]], 1);
}

__global__ void scan_partial_kernel(const int* __restrict__ counts, int* __restrict__ partial) {
    __shared__ int s[256];
    int t = threadIdx.x;
    int i = blockIdx.x * 256 + t;
    s[t] = (i < NN) ? counts[i] : 0;
    __syncthreads();
    for (int off = 128; off; off >>= 1) {
        if (t < off) s[t] += s[t + off];
        __syncthreads();
    }
    if (t == 0) partial[blockIdx.x] = s[0];
}

__global__ void scan_block_kernel(int* __restrict__ partial, int nblk) {
    __shared__ int s[512];
    int t = threadIdx.x;
    s[t] = (t < nblk) ? partial[t] : 0;
    __syncthreads();
    for (int off = 1; off < 512; off <<= 1) {
        int v = (t >= off) ? s[t - off] : 0;
        __syncthreads();
        s[t] += v;
        __syncthreads();
    }
    if (t < nblk) partial[t] = (t == 0) ? 0 : s[t - 1];
}

__global__ void scan_final_kernel(const int* __restrict__ counts, const int* __restrict__ partial,
                                  int* __restrict__ row_start, int* __restrict__ cursor) {
    __shared__ int s[256];
    int t = threadIdx.x;
    int i = blockIdx.x * 256 + t;
    int v = (i < NN) ? counts[i] : 0;
    s[t] = v;
    __syncthreads();
    for (int off = 1; off < 256; off <<= 1) {
        int u = (t >= off) ? s[t - off] : 0;
        __syncthreads();
        s[t] += u;
        __syncthreads();
    }
    int excl = s[t] - v;
    int rs = partial[blockIdx.x] + excl;
    if (i < NN) { row_start[i] = rs; cursor[i] = rs; }
    if (i == 0) row_start[NN] = NE;
}

__global__ void scatter_kernel(const int* __restrict__ src, const int* __restrict__ dst,
                               int* __restrict__ cursor, int* __restrict__ src_sorted) {
    int e = blockIdx.x * 256 + threadIdx.x;
    if (e < NE) {
        int p = atomicAdd(&cursor[dst[e]], 1);
        src_sorted[p] = src[e];
    }
}

// ---------------- fp32 -> bf16 convert ----------------

__global__ void convert_x_kernel(const float* __restrict__ x, unsigned short* __restrict__ xb) {
    int i = blockIdx.x * 256 + threadIdx.x;   // one float4
    const int total = NN * D / 4;
    if (i >= total) return;
    float4 v = ((const float4*)x)[i];
    ushort4 o;
    o.x = f2bf(v.x); o.y = f2bf(v.y); o.z = f2bf(v.z); o.w = f2bf(v.w);
    ((ushort4*)xb)[i] = o;
}

// Bt[n][k] = bf16( k<128 ? Wl[k][n] : Wr[k-128][n] ), layout [ncols][256]
__global__ void wprep_kernel(const float* __restrict__ Wl, const float* __restrict__ Wr,
                             unsigned short* __restrict__ Bt, int ncols) {
    int idx = blockIdx.x * 256 + threadIdx.x;
    if (idx >= ncols * 256) return;
    int n = idx >> 8, k = idx & 255;
    float v = (k < 128) ? Wl[k * ncols + n] : Wr[(k - 128) * ncols + n];
    Bt[idx] = f2bf(v);
}

// ---------------- mean aggregation (bf16 rows): one wave per node ----------------

__global__ void agg_mean_bf_kernel(const unsigned short* __restrict__ feat,
                                   const int* __restrict__ row_start,
                                   const int* __restrict__ src_sorted,
                                   unsigned short* __restrict__ outm) {
    int node = blockIdx.x * 4 + (threadIdx.x >> 6);
    int lane = threadIdx.x & 63;
    if (node >= NN) return;
    int s = row_start[node], e = row_start[node + 1];
    float a0 = 0.f, a1 = 0.f;
    int p = s;
    for (; p + 2 <= e; p += 2) {
        int s0 = src_sorted[p], s1 = src_sorted[p + 1];
        unsigned int v0 = *(const unsigned int*)&feat[(size_t)s0 * D + 2 * lane];
        unsigned int v1 = *(const unsigned int*)&feat[(size_t)s1 * D + 2 * lane];
        a0 += bf2f((unsigned short)v0) + bf2f((unsigned short)v1);
        a1 += bf2f((unsigned short)(v0 >> 16)) + bf2f((unsigned short)(v1 >> 16));
    }
    if (p < e) {
        unsigned int v0 = *(const unsigned int*)&feat[(size_t)src_sorted[p] * D + 2 * lane];
        a0 += bf2f((unsigned short)v0);
        a1 += bf2f((unsigned short)(v0 >> 16));
    }
    int deg = e - s;
    float inv = 1.0f / (float)(deg > 1 ? deg : 1);
    unsigned int o = ((unsigned int)f2bf(a1 * inv) << 16) | (unsigned int)f2bf(a0 * inv);
    *(unsigned int*)&outm[(size_t)node * D + 2 * lane] = o;
}

// ---------------- layer1: hpre = [mean|x] @ [Wl1;Wr1] + bl1 via MFMA ----------------
// BM=64 rows, BN=128 cols, K=256 in two 128-phases. 512 threads = 8 waves:
// wave (wr=w>>1) rows wr*16..+16, (wc=w&1) cols wc*64..+64, N_rep=4.
// Epilogue: rn[node] (row norm), per-block col partial sums -> csc (replicated atomics).

__launch_bounds__(512)
__global__ void linear1_mfma_kernel(const unsigned short* __restrict__ meanb,
                                    const unsigned short* __restrict__ xb,
                                    const unsigned short* __restrict__ Bt,   // [128][256]
                                    const float* __restrict__ bl,            // [128]
                                    unsigned short* __restrict__ hpre,       // [NN][128] bf16
                                    float* __restrict__ rn,                  // [NN]
                                    float* __restrict__ csc) {               // [64][128]
    __shared__ unsigned short sA[64][136];    // pad: stride 272B, 16B-aligned, 2-way banks
    __shared__ unsigned short sB[128][136];
    __shared__ float rowsq[2][64];
    __shared__ float colp[4][128];
    int tid = threadIdx.x;
    int nb = blockIdx.x * 64;
    int w = tid >> 6, lane = tid & 63;
    int wr = w >> 1, wc = w & 1;
    int lr = lane & 15, lg = lane >> 4;

    f32x4 acc[4];
#pragma unroll
    for (int n = 0; n < 4; ++n) acc[n] = (f32x4){0.f, 0.f, 0.f, 0.f};

    for (int ks = 0; ks < 2; ++ks) {
        const unsigned short* srcA = ks ? xb : meanb;
#pragma unroll
        for (int i = 0; i < 2; ++i) {           // A: 64 rows x 16 chunks(8 bf16)
            int ch = tid + i * 512;
            int r = ch >> 4, c8 = ch & 15;
            int node = nb + r;
            uint4 val = make_uint4(0, 0, 0, 0);
            if (node < NN) val = *(const uint4*)&srcA[(size_t)node * D + c8 * 8];
            *(uint4*)&sA[r][c8 * 8] = val;
        }
#pragma unroll
        for (int i = 0; i < 4; ++i) {           // B half: 128 rows x 16 chunks
            int ch = tid + i * 512;
            int n = ch >> 4, c8 = ch & 15;
            *(uint4*)&sB[n][c8 * 8] = *(const uint4*)&Bt[n * K2 + ks * 128 + c8 * 8];
        }
        __syncthreads();
#pragma unroll
        for (int kk = 0; kk < 4; ++kk) {
            short8 a = *(const short8*)&sA[wr * 16 + lr][kk * 32 + lg * 8];
#pragma unroll
            for (int n = 0; n < 4; ++n) {
                short8 b = *(const short8*)&sB[wc * 64 + n * 16 + lr][kk * 32 + lg * 8];
                acc[n] = __builtin_amdgcn_mfma_f32_16x16x32_bf16(a, b, acc[n], 0, 0, 0);
            }
        }
        __syncthreads();
    }

    // epilogue: lane holds rows (wr*16+lg*4+j) j=0..3, cols (wc*64+n*16+lr) n=0..3
    float cp[4];
#pragma unroll
    for (int n = 0; n < 4; ++n) cp[n] = 0.f;
#pragma unroll
    for (int j = 0; j < 4; ++j) {
        int row = wr * 16 + lg * 4 + j;
        int node = nb + row;
        bool valid = node < NN;
        float s = 0.f;
#pragma unroll
        for (int n = 0; n < 4; ++n) {
            float v = acc[n][j] + bl[wc * 64 + n * 16 + lr];
            s += v * v;
            if (valid) {
                hpre[(size_t)node * D + wc * 64 + n * 16 + lr] = f2bf(v);
                cp[n] += v;
            }
        }
#pragma unroll
        for (int off = 1; off <= 8; off <<= 1) s += __shfl_xor(s, off, 64);
        if (lr == 0) rowsq[wc][row] = s;
    }
#pragma unroll
    for (int n = 0; n < 4; ++n) {
        cp[n] += __shfl_xor(cp[n], 16, 64);
        cp[n] += __shfl_xor(cp[n], 32, 64);
    }
    if (lg == 0) {
#pragma unroll
        for (int n = 0; n < 4; ++n) colp[wr][wc * 64 + n * 16 + lr] = cp[n];
    }
    __syncthreads();
    if (tid < 64) {
        int node = nb + tid;
        if (node < NN) rn[node] = sqrtf(1e-6f + rowsq[0][tid] + rowsq[1][tid]);
    } else if (tid >= 128 && tid < 256) {
        int c = tid - 128;
        float t = colp[0][c] + colp[1][c] + colp[2][c] + colp[3][c];
        atomicAdd(&csc[(blockIdx.x & 63) * D + c], t);
    }
}

__global__ void colreduce_kernel(const float* __restrict__ csc, float* __restrict__ colmean) {
    int c = threadIdx.x;
    if (c < D) {
        float s = 0.f;
        for (int j = 0; j < 64; ++j) s += csc[j * D + c];
        colmean[c] = s * (1.0f / (float)NN);
    }
}

// ---------------- pairnorm-scs + relu: hpre(bf16) -> h(bf16) ----------------

__global__ void pairnorm_kernel(const unsigned short* __restrict__ hpre, const float* __restrict__ rn,
                                const float* __restrict__ colmean, unsigned short* __restrict__ hb) {
    int i = blockIdx.x * 256 + threadIdx.x;   // 4 elements
    const int total = NN * D / 4;
    if (i >= total) return;
    int nrow = i >> 5;
    int c4 = i & 31;
    ushort4 v = ((const ushort4*)hpre)[i];
    float riv = NORM_SCALE / rn[nrow];
    float4 cm = ((const float4*)colmean)[c4];
    ushort4 o;
    o.x = f2bf(fmaxf(bf2f(v.x) * riv - cm.x, 0.f));
    o.y = f2bf(fmaxf(bf2f(v.y) * riv - cm.y, 0.f));
    o.z = f2bf(fmaxf(bf2f(v.z) * riv - cm.z, 0.f));
    o.w = f2bf(fmaxf(bf2f(v.w) * riv - cm.w, 0.f));
    ((ushort4*)hb)[i] = o;
}

// ---------------- layer2: out = [mean2|h] @ [Wl2;Wr2] + bl2 via MFMA ----------------
// BM=128 rows, BN=64 cols (full). 512 threads = 8 waves, wave w rows w*16..+16, N_rep=4.

__launch_bounds__(512)
__global__ void linear2_mfma_kernel(const unsigned short* __restrict__ meanb,
                                    const unsigned short* __restrict__ hb,
                                    const unsigned short* __restrict__ Bt2,  // [64][256]
                                    const float* __restrict__ bl2,           // [64]
                                    float* __restrict__ out) {
    __shared__ unsigned short sA[128][136];
    __shared__ unsigned short sB[64][136];
    int tid = threadIdx.x;
    int nb = blockIdx.x * 128;
    int w = tid >> 6, lane = tid & 63;
    int lr = lane & 15, lg = lane >> 4;

    f32x4 acc[4];
#pragma unroll
    for (int n = 0; n < 4; ++n) acc[n] = (f32x4){0.f, 0.f, 0.f, 0.f};

    for (int ks = 0; ks < 2; ++ks) {
        const unsigned short* srcA = ks ? hb : meanb;
#pragma unroll
        for (int i = 0; i < 4; ++i) {           // A: 128 rows x 16 chunks
            int ch = tid + i * 512;
            int r = ch >> 4, c8 = ch & 15;
            int node = nb + r;
            uint4 val = make_uint4(0, 0, 0, 0);
            if (node < NN) val = *(const uint4*)&srcA[(size_t)node * D + c8 * 8];
            *(uint4*)&sA[r][c8 * 8] = val;
        }
#pragma unroll
        for (int i = 0; i < 2; ++i) {           // B half: 64 rows x 16 chunks
            int ch = tid + i * 512;
            int n = ch >> 4, c8 = ch & 15;
            *(uint4*)&sB[n][c8 * 8] = *(const uint4*)&Bt2[n * K2 + ks * 128 + c8 * 8];
        }
        __syncthreads();
#pragma unroll
        for (int kk = 0; kk < 4; ++kk) {
            short8 a = *(const short8*)&sA[w * 16 + lr][kk * 32 + lg * 8];
#pragma unroll
            for (int n = 0; n < 4; ++n) {
                short8 b = *(const short8*)&sB[n * 16 + lr][kk * 32 + lg * 8];
                acc[n] = __builtin_amdgcn_mfma_f32_16x16x32_bf16(a, b, acc[n], 0, 0, 0);
            }
        }
        __syncthreads();
    }
#pragma unroll
    for (int j = 0; j < 4; ++j) {
        int node = nb + w * 16 + lg * 4 + j;
        if (node < NN) {
#pragma unroll
            for (int n = 0; n < 4; ++n)
                out[(size_t)node * DOUT + n * 16 + lr] = acc[n][j] + bl2[n * 16 + lr];
        }
    }
}

// ---------------- launch ----------------

extern "C" void kernel_launch(void* const* d_in, const int* in_sizes, int n_in,
                              void* d_out, int out_size, void* d_ws, size_t ws_size,
                              hipStream_t stream) {
    const float* x   = (const float*)d_in[0];
    const int*   ei  = (const int*)d_in[1];
    const float* Wl1 = (const float*)d_in[2];
    const float* bl1 = (const float*)d_in[3];
    const float* Wr1 = (const float*)d_in[4];
    const float* Wl2 = (const float*)d_in[5];
    const float* bl2 = (const float*)d_in[6];
    const float* Wr2 = (const float*)d_in[7];
    const int* src = ei;
    const int* dst = ei + NE;
    float* out = (float*)d_out;

    char* p = (char*)d_ws;
    auto alloc = [&](size_t bytes) -> void* {
        void* r = (void*)p;
        p += (bytes + 255) & ~(size_t)255;
        return r;
    };
    int* counts      = (int*)alloc((size_t)NN * 4);
    int* cursor      = (int*)alloc((size_t)NN * 4);
    int* row_start   = (int*)alloc((size_t)(NN + 1) * 4);
    int* partial     = (int*)alloc(512 * 4);
    int* src_sorted  = (int*)alloc((size_t)NE * 4);
    unsigned short* xb     = (unsigned short*)alloc((size_t)NN * D * 2);
    unsigned short* meanb  = (unsigned short*)alloc((size_t)NN * D * 2);
    unsigned short* hpre   = (unsigned short*)alloc((size_t)NN * D * 2);
    unsigned short* hb     = (unsigned short*)alloc((size_t)NN * D * 2);
    unsigned short* Bt1    = (unsigned short*)alloc((size_t)D * K2 * 2);
    unsigned short* Bt2    = (unsigned short*)alloc((size_t)DOUT * K2 * 2);
    float* rn        = (float*)alloc((size_t)NN * 4);
    float* csc       = (float*)alloc(64 * D * 4);
    float* colmean   = (float*)alloc(D * 4);

    const int NBLK_SCAN = (NN + 255) / 256;          // 391
    const int NBLK_E    = (NE + 255) / 256;          // 6250
    const int NBLK_AGG  = (NN + 3) / 4;              // 25000
    const int NBLK_CV   = (NN * D / 4 + 255) / 256;  // 12500
    const int NBLK_L1   = (NN + 63) / 64;            // 1563
    const int NBLK_L2   = (NN + 127) / 128;          // 782

    hipMemsetAsync(counts, 0, (size_t)NN * 4, stream);
    hipMemsetAsync(csc, 0, 64 * D * 4, stream);

    // CSR build (shared by both layers)
    hist_kernel<<<NBLK_E, 256, 0, stream>>>(dst, counts);
    scan_partial_kernel<<<NBLK_SCAN, 256, 0, stream>>>(counts, partial);
    scan_block_kernel<<<1, 512, 0, stream>>>(partial, NBLK_SCAN);
    scan_final_kernel<<<NBLK_SCAN, 256, 0, stream>>>(counts, partial, row_start, cursor);
    scatter_kernel<<<NBLK_E, 256, 0, stream>>>(src, dst, cursor, src_sorted);

    // bf16 prep
    convert_x_kernel<<<NBLK_CV, 256, 0, stream>>>(x, xb);
    wprep_kernel<<<(D * K2 + 255) / 256, 256, 0, stream>>>(Wl1, Wr1, Bt1, D);
    wprep_kernel<<<(DOUT * K2 + 255) / 256, 256, 0, stream>>>(Wl2, Wr2, Bt2, DOUT);

    // layer 1
    agg_mean_bf_kernel<<<NBLK_AGG, 256, 0, stream>>>(xb, row_start, src_sorted, meanb);
    linear1_mfma_kernel<<<NBLK_L1, 512, 0, stream>>>(meanb, xb, Bt1, bl1, hpre, rn, csc);
    colreduce_kernel<<<1, 128, 0, stream>>>(csc, colmean);
    pairnorm_kernel<<<NBLK_CV, 256, 0, stream>>>(hpre, rn, colmean, hb);

    // layer 2
    agg_mean_bf_kernel<<<NBLK_AGG, 256, 0, stream>>>(hb, row_start, src_sorted, meanb);
    linear2_mfma_kernel<<<NBLK_L2, 512, 0, stream>>>(meanb, hb, Bt2, bl2, out);
}

// Round 7
// 466.491 us; speedup vs baseline: 1.9682x; 1.1708x over previous
//
#include <hip/hip_runtime.h>

#define NN 100000
#define NE 1600000
#define D  128
#define DOUT 64
#define K2 256
#define NORM_SCALE 1.0f
#define NBUCK 98      // ceil(NN / 1024)
#define BSHIFT 10
#define EPB 4096      // edges per block in binA

using short8 = __attribute__((ext_vector_type(8))) short;
using f32x4  = __attribute__((ext_vector_type(4))) float;

__device__ inline unsigned short f2bf(float f) {
    union { float f; unsigned int u; } v; v.f = f;
    unsigned int r = v.u + 0x7FFFu + ((v.u >> 16) & 1u);
    return (unsigned short)(r >> 16);
}
__device__ inline float bf2f(unsigned short u) {
    union { unsigned int u; float f; } v; v.u = ((unsigned int)u) << 16;
    return v.f;
}

// ---------------- CSR build: hist + scan ----------------

__global__ void hist_kernel(const int* __restrict__ dst, int* __restrict__ counts) {
    int e = blockIdx.x * 256 + threadIdx.x;
    if (e < NE) atomicAdd(&counts[dst[e]], 1);
}

__global__ void scan_partial_kernel(const int* __restrict__ counts, int* __restrict__ partial) {
    __shared__ int s[256];
    int t = threadIdx.x;
    int i = blockIdx.x * 256 + t;
    s[t] = (i < NN) ? counts[i] : 0;
    __syncthreads();
    for (int off = 128; off; off >>= 1) {
        if (t < off) s[t] += s[t + off];
        __syncthreads();
    }
    if (t == 0) partial[blockIdx.x] = s[0];
}

__global__ void scan_block_kernel(int* __restrict__ partial, int nblk) {
    __shared__ int s[512];
    int t = threadIdx.x;
    s[t] = (t < nblk) ? partial[t] : 0;
    __syncthreads();
    for (int off = 1; off < 512; off <<= 1) {
        int v = (t >= off) ? s[t - off] : 0;
        __syncthreads();
        s[t] += v;
        __syncthreads();
    }
    if (t < nblk) partial[t] = (t == 0) ? 0 : s[t - 1];
}

__global__ void scan_final_kernel(const int* __restrict__ counts, const int* __restrict__ partial,
                                  int* __restrict__ row_start, int* __restrict__ cursor) {
    __shared__ int s[256];
    int t = threadIdx.x;
    int i = blockIdx.x * 256 + t;
    int v = (i < NN) ? counts[i] : 0;
    s[t] = v;
    __syncthreads();
    for (int off = 1; off < 256; off <<= 1) {
        int u = (t >= off) ? s[t - off] : 0;
        __syncthreads();
        s[t] += u;
        __syncthreads();
    }
    int excl = s[t] - v;
    int rs = partial[blockIdx.x] + excl;
    if (i < NN) { row_start[i] = rs; cursor[i] = rs; }
    if (i == 0) row_start[NN] = NE;
}

__global__ void init_bc_kernel(const int* __restrict__ row_start, int* __restrict__ bucket_cursor) {
    int b = threadIdx.x;
    if (b < NBUCK) bucket_cursor[b] = row_start[b << BSHIFT];
}

// ---------------- binned scatter, pass A: coarse buckets with block reservation ----------------

__launch_bounds__(256)
__global__ void binA_kernel(const int* __restrict__ src, const int* __restrict__ dst,
                            int* __restrict__ bucket_cursor, unsigned int* __restrict__ binned) {
    __shared__ int cnt[NBUCK];
    __shared__ int gbase[NBUCK];
    int tid = threadIdx.x;
    for (int i = tid; i < NBUCK; i += 256) cnt[i] = 0;
    __syncthreads();
    int base = blockIdx.x * EPB;
    int mysrc[16], mydst[16], myrank[16];
#pragma unroll
    for (int i = 0; i < 16; ++i) {
        int e = base + tid + i * 256;
        if (e < NE) {
            mysrc[i] = src[e];
            int d = dst[e];
            mydst[i] = d;
            myrank[i] = atomicAdd(&cnt[d >> BSHIFT], 1);
        }
    }
    __syncthreads();
    for (int b = tid; b < NBUCK; b += 256)
        gbase[b] = atomicAdd(&bucket_cursor[b], cnt[b]);
    __syncthreads();
#pragma unroll
    for (int i = 0; i < 16; ++i) {
        int e = base + tid + i * 256;
        if (e < NE) {
            int d = mydst[i];
            int b = d >> BSHIFT;
            binned[gbase[b] + myrank[i]] =
                ((unsigned int)(d & 1023) << 17) | (unsigned int)mysrc[i];
        }
    }
}

// ---------------- binned scatter, pass B: fine scatter within L2-resident bucket ----------------

__launch_bounds__(256)
__global__ void binB_kernel(const unsigned int* __restrict__ binned, const int* __restrict__ row_start,
                            int* __restrict__ cursor, int* __restrict__ src_sorted) {
    int b = blockIdx.x >> 2;
    int s4 = blockIdx.x & 3;
    int lo = row_start[b << BSHIFT];
    int nodeHi = (b + 1) << BSHIFT; if (nodeHi > NN) nodeHi = NN;
    int hi = row_start[nodeHi];
    int cnt = hi - lo;
    int s = lo + (cnt * s4) / 4;
    int e = lo + (cnt * (s4 + 1)) / 4;
    for (int i = s + threadIdx.x; i < e; i += 256) {
        unsigned int v = binned[i];
        int node = (b << BSHIFT) + (int)(v >> 17);
        int srcn = (int)(v & 0x1FFFF);
        int p = atomicAdd(&cursor[node], 1);
        src_sorted[p] = srcn;
    }
}

// ---------------- fp32 -> bf16 convert / weight prep ----------------

__global__ void convert_x_kernel(const float* __restrict__ x, unsigned short* __restrict__ xb) {
    int i = blockIdx.x * 256 + threadIdx.x;
    const int total = NN * D / 4;
    if (i >= total) return;
    float4 v = ((const float4*)x)[i];
    ushort4 o;
    o.x = f2bf(v.x); o.y = f2bf(v.y); o.z = f2bf(v.z); o.w = f2bf(v.w);
    ((ushort4*)xb)[i] = o;
}

// Bt[n][k] = bf16( k<128 ? Wl1[k][n] : Wr1[k-128][n] ), [128][256]
__global__ void wprep1_kernel(const float* __restrict__ Wl, const float* __restrict__ Wr,
                              unsigned short* __restrict__ Bt) {
    int idx = blockIdx.x * 256 + threadIdx.x;
    if (idx >= D * K2) return;
    int n = idx >> 8, k = idx & 255;
    float v = (k < 128) ? Wl[k * D + n] : Wr[(k - 128) * D + n];
    Bt[idx] = f2bf(v);
}

// Bt2[n][k]: n<64 -> Wl2[k][n], n>=64 -> Wr2[k][n-64]; [128][128]
__global__ void wprep2_kernel(const float* __restrict__ Wl2, const float* __restrict__ Wr2,
                              unsigned short* __restrict__ Bt) {
    int idx = blockIdx.x * 256 + threadIdx.x;
    if (idx >= 128 * 128) return;
    int n = idx >> 7, k = idx & 127;
    float v = (n < 64) ? Wl2[k * DOUT + n] : Wr2[k * DOUT + (n - 64)];
    Bt[idx] = f2bf(v);
}

// ---------------- layer1 mean aggregation (bf16 rows, 256B/edge): one wave per node ----------------

__global__ void agg_mean_bf_kernel(const unsigned short* __restrict__ feat,
                                   const int* __restrict__ row_start,
                                   const int* __restrict__ src_sorted,
                                   unsigned short* __restrict__ outm) {
    int node = blockIdx.x * 4 + (threadIdx.x >> 6);
    int lane = threadIdx.x & 63;
    if (node >= NN) return;
    int s = row_start[node], e = row_start[node + 1];
    float a0 = 0.f, a1 = 0.f;
    int p = s;
    for (; p + 4 <= e; p += 4) {
        int s0 = src_sorted[p], s1 = src_sorted[p + 1], s2 = src_sorted[p + 2], s3 = src_sorted[p + 3];
        unsigned int v0 = *(const unsigned int*)&feat[(size_t)s0 * D + 2 * lane];
        unsigned int v1 = *(const unsigned int*)&feat[(size_t)s1 * D + 2 * lane];
        unsigned int v2 = *(const unsigned int*)&feat[(size_t)s2 * D + 2 * lane];
        unsigned int v3 = *(const unsigned int*)&feat[(size_t)s3 * D + 2 * lane];
        a0 += bf2f((unsigned short)v0) + bf2f((unsigned short)v1)
            + bf2f((unsigned short)v2) + bf2f((unsigned short)v3);
        a1 += bf2f((unsigned short)(v0 >> 16)) + bf2f((unsigned short)(v1 >> 16))
            + bf2f((unsigned short)(v2 >> 16)) + bf2f((unsigned short)(v3 >> 16));
    }
    for (; p + 2 <= e; p += 2) {
        int s0 = src_sorted[p], s1 = src_sorted[p + 1];
        unsigned int v0 = *(const unsigned int*)&feat[(size_t)s0 * D + 2 * lane];
        unsigned int v1 = *(const unsigned int*)&feat[(size_t)s1 * D + 2 * lane];
        a0 += bf2f((unsigned short)v0) + bf2f((unsigned short)v1);
        a1 += bf2f((unsigned short)(v0 >> 16)) + bf2f((unsigned short)(v1 >> 16));
    }
    if (p < e) {
        unsigned int v0 = *(const unsigned int*)&feat[(size_t)src_sorted[p] * D + 2 * lane];
        a0 += bf2f((unsigned short)v0);
        a1 += bf2f((unsigned short)(v0 >> 16));
    }
    int deg = e - s;
    float inv = 1.0f / (float)(deg > 1 ? deg : 1);
    unsigned int o = ((unsigned int)f2bf(a1 * inv) << 16) | (unsigned int)f2bf(a0 * inv);
    *(unsigned int*)&outm[(size_t)node * D + 2 * lane] = o;
}

// ---------------- layer1: hpre = [mean|x] @ [Wl1;Wr1] + bl1 via MFMA ----------------

__launch_bounds__(512)
__global__ void linear1_mfma_kernel(const unsigned short* __restrict__ meanb,
                                    const unsigned short* __restrict__ xb,
                                    const unsigned short* __restrict__ Bt,   // [128][256]
                                    const float* __restrict__ bl,
                                    unsigned short* __restrict__ hpre,
                                    float* __restrict__ rn,
                                    float* __restrict__ csc) {
    __shared__ unsigned short sA[64][136];
    __shared__ unsigned short sB[128][136];
    __shared__ float rowsq[2][64];
    __shared__ float colp[4][128];
    int tid = threadIdx.x;
    int nb = blockIdx.x * 64;
    int w = tid >> 6, lane = tid & 63;
    int wr = w >> 1, wc = w & 1;
    int lr = lane & 15, lg = lane >> 4;

    f32x4 acc[4];
#pragma unroll
    for (int n = 0; n < 4; ++n) acc[n] = (f32x4){0.f, 0.f, 0.f, 0.f};

    for (int ks = 0; ks < 2; ++ks) {
        const unsigned short* srcA = ks ? xb : meanb;
#pragma unroll
        for (int i = 0; i < 2; ++i) {
            int ch = tid + i * 512;
            int r = ch >> 4, c8 = ch & 15;
            int node = nb + r;
            uint4 val = make_uint4(0, 0, 0, 0);
            if (node < NN) val = *(const uint4*)&srcA[(size_t)node * D + c8 * 8];
            *(uint4*)&sA[r][c8 * 8] = val;
        }
#pragma unroll
        for (int i = 0; i < 4; ++i) {
            int ch = tid + i * 512;
            int n = ch >> 4, c8 = ch & 15;
            *(uint4*)&sB[n][c8 * 8] = *(const uint4*)&Bt[n * K2 + ks * 128 + c8 * 8];
        }
        __syncthreads();
#pragma unroll
        for (int kk = 0; kk < 4; ++kk) {
            short8 a = *(const short8*)&sA[wr * 16 + lr][kk * 32 + lg * 8];
#pragma unroll
            for (int n = 0; n < 4; ++n) {
                short8 b = *(const short8*)&sB[wc * 64 + n * 16 + lr][kk * 32 + lg * 8];
                acc[n] = __builtin_amdgcn_mfma_f32_16x16x32_bf16(a, b, acc[n], 0, 0, 0);
            }
        }
        __syncthreads();
    }

    float cp[4];
#pragma unroll
    for (int n = 0; n < 4; ++n) cp[n] = 0.f;
#pragma unroll
    for (int j = 0; j < 4; ++j) {
        int row = wr * 16 + lg * 4 + j;
        int node = nb + row;
        bool valid = node < NN;
        float s = 0.f;
#pragma unroll
        for (int n = 0; n < 4; ++n) {
            float v = acc[n][j] + bl[wc * 64 + n * 16 + lr];
            s += v * v;
            if (valid) {
                hpre[(size_t)node * D + wc * 64 + n * 16 + lr] = f2bf(v);
                cp[n] += v;
            }
        }
#pragma unroll
        for (int off = 1; off <= 8; off <<= 1) s += __shfl_xor(s, off, 64);
        if (lr == 0) rowsq[wc][row] = s;
    }
#pragma unroll
    for (int n = 0; n < 4; ++n) {
        cp[n] += __shfl_xor(cp[n], 16, 64);
        cp[n] += __shfl_xor(cp[n], 32, 64);
    }
    if (lg == 0) {
#pragma unroll
        for (int n = 0; n < 4; ++n) colp[wr][wc * 64 + n * 16 + lr] = cp[n];
    }
    __syncthreads();
    if (tid < 64) {
        int node = nb + tid;
        if (node < NN) rn[node] = sqrtf(1e-6f + rowsq[0][tid] + rowsq[1][tid]);
    } else if (tid >= 128 && tid < 256) {
        int c = tid - 128;
        float t = colp[0][c] + colp[1][c] + colp[2][c] + colp[3][c];
        atomicAdd(&csc[(blockIdx.x & 63) * D + c], t);
    }
}

__global__ void colreduce_kernel(const float* __restrict__ csc, float* __restrict__ colmean) {
    int c = threadIdx.x;
    if (c < D) {
        float s = 0.f;
        for (int j = 0; j < 64; ++j) s += csc[j * D + c];
        colmean[c] = s * (1.0f / (float)NN);
    }
}

// ---------------- pairnorm-scs + relu ----------------

__global__ void pairnorm_kernel(const unsigned short* __restrict__ hpre, const float* __restrict__ rn,
                                const float* __restrict__ colmean, unsigned short* __restrict__ hb) {
    int i = blockIdx.x * 256 + threadIdx.x;
    const int total = NN * D / 4;
    if (i >= total) return;
    int nrow = i >> 5;
    int c4 = i & 31;
    ushort4 v = ((const ushort4*)hpre)[i];
    float riv = NORM_SCALE / rn[nrow];
    float4 cm = ((const float4*)colmean)[c4];
    ushort4 o;
    o.x = f2bf(fmaxf(bf2f(v.x) * riv - cm.x, 0.f));
    o.y = f2bf(fmaxf(bf2f(v.y) * riv - cm.y, 0.f));
    o.z = f2bf(fmaxf(bf2f(v.z) * riv - cm.z, 0.f));
    o.w = f2bf(fmaxf(bf2f(v.w) * riv - cm.w, 0.f));
    ((ushort4*)hb)[i] = o;
}

// ---------------- layer2 GEMM first: z = bf16(h@Wl2), r = h@Wr2 + bl2 ----------------

__launch_bounds__(512)
__global__ void linear2_pre_kernel(const unsigned short* __restrict__ hb,
                                   const unsigned short* __restrict__ Bt2,   // [128][128]
                                   const float* __restrict__ bl2,
                                   unsigned short* __restrict__ z,           // [NN][64] bf16
                                   float* __restrict__ r) {                  // [NN][64] f32
    __shared__ unsigned short sA[64][136];
    __shared__ unsigned short sB[128][136];
    int tid = threadIdx.x;
    int nb = blockIdx.x * 64;
    int w = tid >> 6, lane = tid & 63;
    int wr = w >> 1, wc = w & 1;
    int lr = lane & 15, lg = lane >> 4;

    f32x4 acc[4];
#pragma unroll
    for (int n = 0; n < 4; ++n) acc[n] = (f32x4){0.f, 0.f, 0.f, 0.f};

#pragma unroll
    for (int i = 0; i < 2; ++i) {
        int ch = tid + i * 512;
        int rr = ch >> 4, c8 = ch & 15;
        int node = nb + rr;
        uint4 val = make_uint4(0, 0, 0, 0);
        if (node < NN) val = *(const uint4*)&hb[(size_t)node * D + c8 * 8];
        *(uint4*)&sA[rr][c8 * 8] = val;
    }
#pragma unroll
    for (int i = 0; i < 4; ++i) {
        int ch = tid + i * 512;
        int n = ch >> 4, c8 = ch & 15;
        *(uint4*)&sB[n][c8 * 8] = *(const uint4*)&Bt2[n * 128 + c8 * 8];
    }
    __syncthreads();
#pragma unroll
    for (int kk = 0; kk < 4; ++kk) {
        short8 a = *(const short8*)&sA[wr * 16 + lr][kk * 32 + lg * 8];
#pragma unroll
        for (int n = 0; n < 4; ++n) {
            short8 b = *(const short8*)&sB[wc * 64 + n * 16 + lr][kk * 32 + lg * 8];
            acc[n] = __builtin_amdgcn_mfma_f32_16x16x32_bf16(a, b, acc[n], 0, 0, 0);
        }
    }
#pragma unroll
    for (int j = 0; j < 4; ++j) {
        int node = nb + wr * 16 + lg * 4 + j;
        if (node < NN) {
#pragma unroll
            for (int n = 0; n < 4; ++n) {
                int c = n * 16 + lr;
                float v = acc[n][j];
                if (wc == 0) z[(size_t)node * DOUT + c] = f2bf(v);
                else         r[(size_t)node * DOUT + c] = v + bl2[c];
            }
        }
    }
}

// ---------------- fused layer2 aggregation: out = mean(z) + r ----------------
// one wave per node; lanes<32 handle even edge, lanes>=32 odd edge; 128B z rows.

__global__ void agg2_fused_kernel(const unsigned short* __restrict__ z,
                                  const float* __restrict__ r,
                                  const int* __restrict__ row_start,
                                  const int* __restrict__ src_sorted,
                                  float* __restrict__ out) {
    int node = blockIdx.x * 4 + (threadIdx.x >> 6);
    int lane = threadIdx.x & 63;
    if (node >= NN) return;
    int s = row_start[node], e = row_start[node + 1];
    int half = lane >> 5;          // 0 or 1
    int col2 = lane & 31;          // column pair index
    float a0 = 0.f, a1 = 0.f;
    int p = s;
    for (; p + 4 <= e; p += 4) {
        int i0 = src_sorted[p + half];
        int i1 = src_sorted[p + 2 + half];
        unsigned int v0 = *(const unsigned int*)&z[(size_t)i0 * DOUT + 2 * col2];
        unsigned int v1 = *(const unsigned int*)&z[(size_t)i1 * DOUT + 2 * col2];
        a0 += bf2f((unsigned short)v0) + bf2f((unsigned short)v1);
        a1 += bf2f((unsigned short)(v0 >> 16)) + bf2f((unsigned short)(v1 >> 16));
    }
    if (p + 2 <= e) {
        int i0 = src_sorted[p + half];
        unsigned int v0 = *(const unsigned int*)&z[(size_t)i0 * DOUT + 2 * col2];
        a0 += bf2f((unsigned short)v0);
        a1 += bf2f((unsigned short)(v0 >> 16));
        p += 2;
    }
    if (p < e && half == 0) {
        unsigned int v0 = *(const unsigned int*)&z[(size_t)src_sorted[p] * DOUT + 2 * col2];
        a0 += bf2f((unsigned short)v0);
        a1 += bf2f((unsigned short)(v0 >> 16));
    }
    a0 += __shfl_xor(a0, 32, 64);
    a1 += __shfl_xor(a1, 32, 64);
    if (half == 0) {
        int deg = e - s;
        float inv = 1.0f / (float)(deg > 1 ? deg : 1);
        float2 rv = *(const float2*)&r[(size_t)node * DOUT + 2 * col2];
        float2 o;
        o.x = a0 * inv + rv.x;
        o.y = a1 * inv + rv.y;
        *(float2*)&out[(size_t)node * DOUT + 2 * col2] = o;
    }
}

// ---------------- launch ----------------

extern "C" void kernel_launch(void* const* d_in, const int* in_sizes, int n_in,
                              void* d_out, int out_size, void* d_ws, size_t ws_size,
                              hipStream_t stream) {
    const float* x   = (const float*)d_in[0];
    const int*   ei  = (const int*)d_in[1];
    const float* Wl1 = (const float*)d_in[2];
    const float* bl1 = (const float*)d_in[3];
    const float* Wr1 = (const float*)d_in[4];
    const float* Wl2 = (const float*)d_in[5];
    const float* bl2 = (const float*)d_in[6];
    const float* Wr2 = (const float*)d_in[7];
    const int* src = ei;
    const int* dst = ei + NE;
    float* out = (float*)d_out;

    char* p = (char*)d_ws;
    auto alloc = [&](size_t bytes) -> void* {
        void* r = (void*)p;
        p += (bytes + 255) & ~(size_t)255;
        return r;
    };
    int* counts      = (int*)alloc((size_t)NN * 4);
    int* cursor      = (int*)alloc((size_t)NN * 4);
    int* row_start   = (int*)alloc((size_t)(NN + 1) * 4);
    int* partial     = (int*)alloc(512 * 4);
    int* bucket_cursor = (int*)alloc(NBUCK * 4);
    unsigned int* binned = (unsigned int*)alloc((size_t)NE * 4);
    int* src_sorted  = (int*)alloc((size_t)NE * 4);
    unsigned short* xb     = (unsigned short*)alloc((size_t)NN * D * 2);
    unsigned short* meanb  = (unsigned short*)alloc((size_t)NN * D * 2);  // layer2: aliases z
    unsigned short* hpre   = (unsigned short*)alloc((size_t)NN * D * 2);  // layer2: aliases r (f32 NN*64)
    unsigned short* hb     = (unsigned short*)alloc((size_t)NN * D * 2);
    unsigned short* Bt1    = (unsigned short*)alloc((size_t)D * K2 * 2);
    unsigned short* Bt2    = (unsigned short*)alloc((size_t)128 * 128 * 2);
    float* rn        = (float*)alloc((size_t)NN * 4);
    float* csc       = (float*)alloc(64 * D * 4);
    float* colmean   = (float*)alloc(D * 4);

    unsigned short* z = meanb;              // [NN][64] bf16 (12.8 MB of 25.6)
    float* rbuf       = (float*)hpre;       // [NN][64] f32  (exactly 25.6 MB)

    const int NBLK_SCAN = (NN + 255) / 256;          // 391
    const int NBLK_E    = (NE + 255) / 256;          // 6250
    const int NBLK_AGG  = (NN + 3) / 4;              // 25000
    const int NBLK_CV   = (NN * D / 4 + 255) / 256;  // 12500
    const int NBLK_L    = (NN + 63) / 64;            // 1563
    const int NBLK_BINA = (NE + EPB - 1) / EPB;      // 391

    hipMemsetAsync(counts, 0, (size_t)NN * 4, stream);
    hipMemsetAsync(csc, 0, 64 * D * 4, stream);

    // CSR build
    hist_kernel<<<NBLK_E, 256, 0, stream>>>(dst, counts);
    scan_partial_kernel<<<NBLK_SCAN, 256, 0, stream>>>(counts, partial);
    scan_block_kernel<<<1, 512, 0, stream>>>(partial, NBLK_SCAN);
    scan_final_kernel<<<NBLK_SCAN, 256, 0, stream>>>(counts, partial, row_start, cursor);
    init_bc_kernel<<<1, 128, 0, stream>>>(row_start, bucket_cursor);
    binA_kernel<<<NBLK_BINA, 256, 0, stream>>>(src, dst, bucket_cursor, binned);
    binB_kernel<<<NBUCK * 4, 256, 0, stream>>>(binned, row_start, cursor, src_sorted);

    // bf16 prep
    convert_x_kernel<<<NBLK_CV, 256, 0, stream>>>(x, xb);
    wprep1_kernel<<<(D * K2 + 255) / 256, 256, 0, stream>>>(Wl1, Wr1, Bt1);
    wprep2_kernel<<<(128 * 128 + 255) / 256, 256, 0, stream>>>(Wl2, Wr2, Bt2);

    // layer 1
    agg_mean_bf_kernel<<<NBLK_AGG, 256, 0, stream>>>(xb, row_start, src_sorted, meanb);
    linear1_mfma_kernel<<<NBLK_L, 512, 0, stream>>>(meanb, xb, Bt1, bl1, hpre, rn, csc);
    colreduce_kernel<<<1, 128, 0, stream>>>(csc, colmean);
    pairnorm_kernel<<<NBLK_CV, 256, 0, stream>>>(hpre, rn, colmean, hb);

    // layer 2: GEMM first, then fused aggregation (mean(h@Wl2) == mean(h)@Wl2)
    linear2_pre_kernel<<<NBLK_L, 512, 0, stream>>>(hb, Bt2, bl2, z, rbuf);
    agg2_fused_kernel<<<NBLK_AGG, 256, 0, stream>>>(z, rbuf, row_start, src_sorted, out);
}

// Round 9
// 336.702 us; speedup vs baseline: 2.7269x; 1.3855x over previous
//
#include <hip/hip_runtime.h>

#define NN 100000
#define NE 1600000
#define D  128
#define DOUT 64
#define K2 256
#define NORM_SCALE 1.0f
#define BSHIFT 9
#define NBUCK 196     // ceil(NN / 512)
#define BCAP 10240    // fixed bin capacity (mean 8163, std 90 -> +23 sigma)
#define EPB 4096      // edges per block in binA

using short8 = __attribute__((ext_vector_type(8))) short;
using f32x4  = __attribute__((ext_vector_type(4))) float;

__device__ inline unsigned short f2bf(float f) {
    union { float f; unsigned int u; } v; v.f = f;
    unsigned int r = v.u + 0x7FFFu + ((v.u >> 16) & 1u);
    return (unsigned short)(r >> 16);
}
__device__ inline float bf2f(unsigned short u) {
    union { unsigned int u; float f; } v; v.u = ((unsigned int)u) << 16;
    return v.f;
}

// ---------------- binning pipeline ----------------

__global__ void init_cursor_kernel(int* __restrict__ bucket_cursor) {
    int b = threadIdx.x;
    if (b < NBUCK) bucket_cursor[b] = b * BCAP;
}

// pass A: coarse buckets with block reservation into fixed-capacity bins
__launch_bounds__(256)
__global__ void binA_kernel(const int* __restrict__ src, const int* __restrict__ dst,
                            int* __restrict__ bucket_cursor, unsigned int* __restrict__ binned) {
    __shared__ int cnt[NBUCK];
    __shared__ int gbase[NBUCK];
    int tid = threadIdx.x;
    for (int i = tid; i < NBUCK; i += 256) cnt[i] = 0;
    __syncthreads();
    int base = blockIdx.x * EPB;
    int mysrc[16], mydst[16], myrank[16];
#pragma unroll
    for (int i = 0; i < 16; ++i) {
        int e = base + tid + i * 256;
        if (e < NE) {
            mysrc[i] = src[e];
            int d = dst[e];
            mydst[i] = d;
            myrank[i] = atomicAdd(&cnt[d >> BSHIFT], 1);
        }
    }
    __syncthreads();
    for (int b = tid; b < NBUCK; b += 256)
        gbase[b] = atomicAdd(&bucket_cursor[b], cnt[b]);
    __syncthreads();
#pragma unroll
    for (int i = 0; i < 16; ++i) {
        int e = base + tid + i * 256;
        if (e < NE) {
            int d = mydst[i];
            int b = d >> BSHIFT;
            binned[gbase[b] + myrank[i]] =
                ((unsigned int)(d & 511) << 17) | (unsigned int)mysrc[i];
        }
    }
}

// scan of bucket totals -> bucket_base (global CSR base per bucket)
__global__ void bucket_scan_kernel(const int* __restrict__ bucket_cursor,
                                   int* __restrict__ bucket_base, int* __restrict__ row_start) {
    __shared__ int sh[256];
    int t = threadIdx.x;
    int v = (t < NBUCK) ? (bucket_cursor[t] - t * BCAP) : 0;
    sh[t] = v;
    __syncthreads();
    for (int off = 1; off < 256; off <<= 1) {
        int u = (t >= off) ? sh[t - off] : 0;
        __syncthreads();
        sh[t] += u;
        __syncthreads();
    }
    if (t < NBUCK) bucket_base[t] = sh[t] - v;   // exclusive
    if (t == 0) row_start[NN] = NE;
}

// pass B: per-bucket LDS counting sort -> coalesced src_sorted + row_start
__launch_bounds__(1024)
__global__ void binB_sort_kernel(const unsigned int* __restrict__ binned,
                                 const int* __restrict__ bucket_cursor,
                                 const int* __restrict__ bucket_base,
                                 int* __restrict__ row_start,
                                 int* __restrict__ src_sorted) {
    __shared__ unsigned int ebuf[BCAP];   // 40 KB payload
    __shared__ int hist[512];
    __shared__ int cur[512];
    __shared__ int wsum[8];
    int b = blockIdx.x;
    int tid = threadIdx.x;
    int base = b * BCAP;
    int cnt = bucket_cursor[b] - base;
    int gb = bucket_base[b];

    if (tid < 512) hist[tid] = 0;
    __syncthreads();

    unsigned int ev[10];
#pragma unroll
    for (int j = 0; j < 10; ++j) {
        int i = tid + j * 1024;
        if (i < cnt) {
            unsigned int v = binned[base + i];
            ev[j] = v;
            atomicAdd(&hist[v >> 17], 1);
        }
    }
    __syncthreads();

    // exclusive scan of hist[512] (threads 0..511: 8 waves)
    int incl = 0;
    if (tid < 512) {
        int lane = tid & 63, w = tid >> 6;
        incl = hist[tid];
        for (int off = 1; off < 64; off <<= 1) {
            int u = __shfl_up(incl, off, 64);
            if (lane >= off) incl += u;
        }
        if (lane == 63) wsum[w] = incl;
    }
    __syncthreads();
    if (tid == 0) {
        int acc = 0;
#pragma unroll
        for (int j = 0; j < 8; ++j) { int t = wsum[j]; wsum[j] = acc; acc += t; }
    }
    __syncthreads();
    if (tid < 512) {
        incl += wsum[tid >> 6];
        int ex = incl - hist[tid];
        cur[tid] = ex;
        int node = (b << BSHIFT) + tid;
        if (node < NN) row_start[node] = gb + ex;
    }
    __syncthreads();

    // scatter payload into LDS at sorted position
#pragma unroll
    for (int j = 0; j < 10; ++j) {
        int i = tid + j * 1024;
        if (i < cnt) {
            unsigned int v = ev[j];
            int p = atomicAdd(&cur[v >> 17], 1);
            ebuf[p] = v & 0x1FFFFu;
        }
    }
    __syncthreads();

    // fully coalesced contiguous write-out
    for (int i = tid; i < cnt; i += 1024)
        src_sorted[gb + i] = (int)ebuf[i];
}

// ---------------- fp32 -> bf16 convert / weight prep ----------------

__global__ void convert_x_kernel(const float* __restrict__ x, unsigned short* __restrict__ xb) {
    int i = blockIdx.x * 256 + threadIdx.x;
    const int total = NN * D / 4;
    if (i >= total) return;
    float4 v = ((const float4*)x)[i];
    ushort4 o;
    o.x = f2bf(v.x); o.y = f2bf(v.y); o.z = f2bf(v.z); o.w = f2bf(v.w);
    ((ushort4*)xb)[i] = o;
}

// Bt[n][k] = bf16( k<128 ? Wl1[k][n] : Wr1[k-128][n] ), [128][256]
__global__ void wprep1_kernel(const float* __restrict__ Wl, const float* __restrict__ Wr,
                              unsigned short* __restrict__ Bt) {
    int idx = blockIdx.x * 256 + threadIdx.x;
    if (idx >= D * K2) return;
    int n = idx >> 8, k = idx & 255;
    float v = (k < 128) ? Wl[k * D + n] : Wr[(k - 128) * D + n];
    Bt[idx] = f2bf(v);
}

// Bt2[n][k]: n<64 -> Wl2[k][n], n>=64 -> Wr2[k][n-64]; [128][128]
__global__ void wprep2_kernel(const float* __restrict__ Wl2, const float* __restrict__ Wr2,
                              unsigned short* __restrict__ Bt) {
    int idx = blockIdx.x * 256 + threadIdx.x;
    if (idx >= 128 * 128) return;
    int n = idx >> 7, k = idx & 127;
    float v = (n < 64) ? Wl2[k * DOUT + n] : Wr2[k * DOUT + (n - 64)];
    Bt[idx] = f2bf(v);
}

// ---------------- layer1 mean aggregation (bf16 rows, 256B/edge): one wave per node ----------------

__global__ void agg_mean_bf_kernel(const unsigned short* __restrict__ feat,
                                   const int* __restrict__ row_start,
                                   const int* __restrict__ src_sorted,
                                   unsigned short* __restrict__ outm) {
    int node = blockIdx.x * 4 + (threadIdx.x >> 6);
    int lane = threadIdx.x & 63;
    if (node >= NN) return;
    int s = row_start[node], e = row_start[node + 1];
    float a0 = 0.f, a1 = 0.f;
    int p = s;
    for (; p + 4 <= e; p += 4) {
        int s0 = src_sorted[p], s1 = src_sorted[p + 1], s2 = src_sorted[p + 2], s3 = src_sorted[p + 3];
        unsigned int v0 = *(const unsigned int*)&feat[(size_t)s0 * D + 2 * lane];
        unsigned int v1 = *(const unsigned int*)&feat[(size_t)s1 * D + 2 * lane];
        unsigned int v2 = *(const unsigned int*)&feat[(size_t)s2 * D + 2 * lane];
        unsigned int v3 = *(const unsigned int*)&feat[(size_t)s3 * D + 2 * lane];
        a0 += bf2f((unsigned short)v0) + bf2f((unsigned short)v1)
            + bf2f((unsigned short)v2) + bf2f((unsigned short)v3);
        a1 += bf2f((unsigned short)(v0 >> 16)) + bf2f((unsigned short)(v1 >> 16))
            + bf2f((unsigned short)(v2 >> 16)) + bf2f((unsigned short)(v3 >> 16));
    }
    for (; p + 2 <= e; p += 2) {
        int s0 = src_sorted[p], s1 = src_sorted[p + 1];
        unsigned int v0 = *(const unsigned int*)&feat[(size_t)s0 * D + 2 * lane];
        unsigned int v1 = *(const unsigned int*)&feat[(size_t)s1 * D + 2 * lane];
        a0 += bf2f((unsigned short)v0) + bf2f((unsigned short)v1);
        a1 += bf2f((unsigned short)(v0 >> 16)) + bf2f((unsigned short)(v1 >> 16));
    }
    if (p < e) {
        unsigned int v0 = *(const unsigned int*)&feat[(size_t)src_sorted[p] * D + 2 * lane];
        a0 += bf2f((unsigned short)v0);
        a1 += bf2f((unsigned short)(v0 >> 16));
    }
    int deg = e - s;
    float inv = 1.0f / (float)(deg > 1 ? deg : 1);
    unsigned int o = ((unsigned int)f2bf(a1 * inv) << 16) | (unsigned int)f2bf(a0 * inv);
    *(unsigned int*)&outm[(size_t)node * D + 2 * lane] = o;
}

// ---------------- layer1: hpre = [mean|x] @ [Wl1;Wr1] + bl1 via MFMA ----------------

__launch_bounds__(512)
__global__ void linear1_mfma_kernel(const unsigned short* __restrict__ meanb,
                                    const unsigned short* __restrict__ xb,
                                    const unsigned short* __restrict__ Bt,   // [128][256]
                                    const float* __restrict__ bl,
                                    unsigned short* __restrict__ hpre,
                                    float* __restrict__ rn,
                                    float* __restrict__ csc) {
    __shared__ unsigned short sA[64][136];
    __shared__ unsigned short sB[128][136];
    __shared__ float rowsq[2][64];
    __shared__ float colp[4][128];
    int tid = threadIdx.x;
    int nb = blockIdx.x * 64;
    int w = tid >> 6, lane = tid & 63;
    int wr = w >> 1, wc = w & 1;
    int lr = lane & 15, lg = lane >> 4;

    f32x4 acc[4];
#pragma unroll
    for (int n = 0; n < 4; ++n) acc[n] = (f32x4){0.f, 0.f, 0.f, 0.f};

    for (int ks = 0; ks < 2; ++ks) {
        const unsigned short* srcA = ks ? xb : meanb;
#pragma unroll
        for (int i = 0; i < 2; ++i) {
            int ch = tid + i * 512;
            int r = ch >> 4, c8 = ch & 15;
            int node = nb + r;
            uint4 val = make_uint4(0, 0, 0, 0);
            if (node < NN) val = *(const uint4*)&srcA[(size_t)node * D + c8 * 8];
            *(uint4*)&sA[r][c8 * 8] = val;
        }
#pragma unroll
        for (int i = 0; i < 4; ++i) {
            int ch = tid + i * 512;
            int n = ch >> 4, c8 = ch & 15;
            *(uint4*)&sB[n][c8 * 8] = *(const uint4*)&Bt[n * K2 + ks * 128 + c8 * 8];
        }
        __syncthreads();
#pragma unroll
        for (int kk = 0; kk < 4; ++kk) {
            short8 a = *(const short8*)&sA[wr * 16 + lr][kk * 32 + lg * 8];
#pragma unroll
            for (int n = 0; n < 4; ++n) {
                short8 b = *(const short8*)&sB[wc * 64 + n * 16 + lr][kk * 32 + lg * 8];
                acc[n] = __builtin_amdgcn_mfma_f32_16x16x32_bf16(a, b, acc[n], 0, 0, 0);
            }
        }
        __syncthreads();
    }

    float cp[4];
#pragma unroll
    for (int n = 0; n < 4; ++n) cp[n] = 0.f;
#pragma unroll
    for (int j = 0; j < 4; ++j) {
        int row = wr * 16 + lg * 4 + j;
        int node = nb + row;
        bool valid = node < NN;
        float s = 0.f;
#pragma unroll
        for (int n = 0; n < 4; ++n) {
            float v = acc[n][j] + bl[wc * 64 + n * 16 + lr];
            s += v * v;
            if (valid) {
                hpre[(size_t)node * D + wc * 64 + n * 16 + lr] = f2bf(v);
                cp[n] += v;
            }
        }
#pragma unroll
        for (int off = 1; off <= 8; off <<= 1) s += __shfl_xor(s, off, 64);
        if (lr == 0) rowsq[wc][row] = s;
    }
#pragma unroll
    for (int n = 0; n < 4; ++n) {
        cp[n] += __shfl_xor(cp[n], 16, 64);
        cp[n] += __shfl_xor(cp[n], 32, 64);
    }
    if (lg == 0) {
#pragma unroll
        for (int n = 0; n < 4; ++n) colp[wr][wc * 64 + n * 16 + lr] = cp[n];
    }
    __syncthreads();
    if (tid < 64) {
        int node = nb + tid;
        if (node < NN) rn[node] = sqrtf(1e-6f + rowsq[0][tid] + rowsq[1][tid]);
    } else if (tid >= 128 && tid < 256) {
        int c = tid - 128;
        float t = colp[0][c] + colp[1][c] + colp[2][c] + colp[3][c];
        atomicAdd(&csc[(blockIdx.x & 63) * D + c], t);
    }
}

__global__ void colreduce_kernel(const float* __restrict__ csc, float* __restrict__ colmean) {
    int c = threadIdx.x;
    if (c < D) {
        float s = 0.f;
        for (int j = 0; j < 64; ++j) s += csc[j * D + c];
        colmean[c] = s * (1.0f / (float)NN);
    }
}

// ---------------- pairnorm-scs + relu ----------------

__global__ void pairnorm_kernel(const unsigned short* __restrict__ hpre, const float* __restrict__ rn,
                                const float* __restrict__ colmean, unsigned short* __restrict__ hb) {
    int i = blockIdx.x * 256 + threadIdx.x;
    const int total = NN * D / 4;
    if (i >= total) return;
    int nrow = i >> 5;
    int c4 = i & 31;
    ushort4 v = ((const ushort4*)hpre)[i];
    float riv = NORM_SCALE / rn[nrow];
    float4 cm = ((const float4*)colmean)[c4];
    ushort4 o;
    o.x = f2bf(fmaxf(bf2f(v.x) * riv - cm.x, 0.f));
    o.y = f2bf(fmaxf(bf2f(v.y) * riv - cm.y, 0.f));
    o.z = f2bf(fmaxf(bf2f(v.z) * riv - cm.z, 0.f));
    o.w = f2bf(fmaxf(bf2f(v.w) * riv - cm.w, 0.f));
    ((ushort4*)hb)[i] = o;
}

// ---------------- layer2 GEMM first: z = bf16(h@Wl2), r = h@Wr2 + bl2 ----------------

__launch_bounds__(512)
__global__ void linear2_pre_kernel(const unsigned short* __restrict__ hb,
                                   const unsigned short* __restrict__ Bt2,   // [128][128]
                                   const float* __restrict__ bl2,
                                   unsigned short* __restrict__ z,           // [NN][64] bf16
                                   float* __restrict__ r) {                  // [NN][64] f32
    __shared__ unsigned short sA[64][136];
    __shared__ unsigned short sB[128][136];
    int tid = threadIdx.x;
    int nb = blockIdx.x * 64;
    int w = tid >> 6, lane = tid & 63;
    int wr = w >> 1, wc = w & 1;
    int lr = lane & 15, lg = lane >> 4;

    f32x4 acc[4];
#pragma unroll
    for (int n = 0; n < 4; ++n) acc[n] = (f32x4){0.f, 0.f, 0.f, 0.f};

#pragma unroll
    for (int i = 0; i < 2; ++i) {
        int ch = tid + i * 512;
        int rr = ch >> 4, c8 = ch & 15;
        int node = nb + rr;
        uint4 val = make_uint4(0, 0, 0, 0);
        if (node < NN) val = *(const uint4*)&hb[(size_t)node * D + c8 * 8];
        *(uint4*)&sA[rr][c8 * 8] = val;
    }
#pragma unroll
    for (int i = 0; i < 4; ++i) {
        int ch = tid + i * 512;
        int n = ch >> 4, c8 = ch & 15;
        *(uint4*)&sB[n][c8 * 8] = *(const uint4*)&Bt2[n * 128 + c8 * 8];
    }
    __syncthreads();
#pragma unroll
    for (int kk = 0; kk < 4; ++kk) {
        short8 a = *(const short8*)&sA[wr * 16 + lr][kk * 32 + lg * 8];
#pragma unroll
        for (int n = 0; n < 4; ++n) {
            short8 b = *(const short8*)&sB[wc * 64 + n * 16 + lr][kk * 32 + lg * 8];
            acc[n] = __builtin_amdgcn_mfma_f32_16x16x32_bf16(a, b, acc[n], 0, 0, 0);
        }
    }
#pragma unroll
    for (int j = 0; j < 4; ++j) {
        int node = nb + wr * 16 + lg * 4 + j;
        if (node < NN) {
#pragma unroll
            for (int n = 0; n < 4; ++n) {
                int c = n * 16 + lr;
                float v = acc[n][j];
                if (wc == 0) z[(size_t)node * DOUT + c] = f2bf(v);
                else         r[(size_t)node * DOUT + c] = v + bl2[c];
            }
        }
    }
}

// ---------------- fused layer2 aggregation: out = mean(z) + r ----------------

__global__ void agg2_fused_kernel(const unsigned short* __restrict__ z,
                                  const float* __restrict__ r,
                                  const int* __restrict__ row_start,
                                  const int* __restrict__ src_sorted,
                                  float* __restrict__ out) {
    int node = blockIdx.x * 4 + (threadIdx.x >> 6);
    int lane = threadIdx.x & 63;
    if (node >= NN) return;
    int s = row_start[node], e = row_start[node + 1];
    int half = lane >> 5;          // 0 or 1
    int col2 = lane & 31;          // column pair index
    float a0 = 0.f, a1 = 0.f;
    int p = s;
    for (; p + 4 <= e; p += 4) {
        int i0 = src_sorted[p + half];
        int i1 = src_sorted[p + 2 + half];
        unsigned int v0 = *(const unsigned int*)&z[(size_t)i0 * DOUT + 2 * col2];
        unsigned int v1 = *(const unsigned int*)&z[(size_t)i1 * DOUT + 2 * col2];
        a0 += bf2f((unsigned short)v0) + bf2f((unsigned short)v1);
        a1 += bf2f((unsigned short)(v0 >> 16)) + bf2f((unsigned short)(v1 >> 16));
    }
    if (p + 2 <= e) {
        int i0 = src_sorted[p + half];
        unsigned int v0 = *(const unsigned int*)&z[(size_t)i0 * DOUT + 2 * col2];
        a0 += bf2f((unsigned short)v0);
        a1 += bf2f((unsigned short)(v0 >> 16));
        p += 2;
    }
    if (p < e && half == 0) {
        unsigned int v0 = *(const unsigned int*)&z[(size_t)src_sorted[p] * DOUT + 2 * col2];
        a0 += bf2f((unsigned short)v0);
        a1 += bf2f((unsigned short)(v0 >> 16));
    }
    a0 += __shfl_xor(a0, 32, 64);
    a1 += __shfl_xor(a1, 32, 64);
    if (half == 0) {
        int deg = e - s;
        float inv = 1.0f / (float)(deg > 1 ? deg : 1);
        float2 rv = *(const float2*)&r[(size_t)node * DOUT + 2 * col2];
        float2 o;
        o.x = a0 * inv + rv.x;
        o.y = a1 * inv + rv.y;
        *(float2*)&out[(size_t)node * DOUT + 2 * col2] = o;
    }
}

// ---------------- launch ----------------

extern "C" void kernel_launch(void* const* d_in, const int* in_sizes, int n_in,
                              void* d_out, int out_size, void* d_ws, size_t ws_size,
                              hipStream_t stream) {
    const float* x   = (const float*)d_in[0];
    const int*   ei  = (const int*)d_in[1];
    const float* Wl1 = (const float*)d_in[2];
    const float* bl1 = (const float*)d_in[3];
    const float* Wr1 = (const float*)d_in[4];
    const float* Wl2 = (const float*)d_in[5];
    const float* bl2 = (const float*)d_in[6];
    const float* Wr2 = (const float*)d_in[7];
    const int* src = ei;
    const int* dst = ei + NE;
    float* out = (float*)d_out;

    char* p = (char*)d_ws;
    auto alloc = [&](size_t bytes) -> void* {
        void* r = (void*)p;
        p += (bytes + 255) & ~(size_t)255;
        return r;
    };
    int* bucket_cursor = (int*)alloc(NBUCK * 4);
    int* bucket_base   = (int*)alloc(NBUCK * 4);
    int* row_start     = (int*)alloc((size_t)(NN + 1) * 4);
    unsigned int* binned = (unsigned int*)alloc((size_t)NBUCK * BCAP * 4);
    int* src_sorted    = (int*)alloc((size_t)NE * 4);
    unsigned short* xb     = (unsigned short*)alloc((size_t)NN * D * 2);
    unsigned short* meanb  = (unsigned short*)alloc((size_t)NN * D * 2);  // layer2: aliases z
    unsigned short* hpre   = (unsigned short*)alloc((size_t)NN * D * 2);  // layer2: aliases r
    unsigned short* hb     = (unsigned short*)alloc((size_t)NN * D * 2);
    unsigned short* Bt1    = (unsigned short*)alloc((size_t)D * K2 * 2);
    unsigned short* Bt2    = (unsigned short*)alloc((size_t)128 * 128 * 2);
    float* rn        = (float*)alloc((size_t)NN * 4);
    float* csc       = (float*)alloc(64 * D * 4);
    float* colmean   = (float*)alloc(D * 4);

    unsigned short* z = meanb;              // [NN][64] bf16
    float* rbuf       = (float*)hpre;       // [NN][64] f32

    const int NBLK_AGG  = (NN + 3) / 4;              // 25000
    const int NBLK_CV   = (NN * D / 4 + 255) / 256;  // 12500
    const int NBLK_L    = (NN + 63) / 64;            // 1563
    const int NBLK_BINA = (NE + EPB - 1) / EPB;      // 391

    hipMemsetAsync(csc, 0, 64 * D * 4, stream);

    // binning + CSR (row_start comes out of the bucket sort)
    init_cursor_kernel<<<1, 256, 0, stream>>>(bucket_cursor);
    binA_kernel<<<NBLK_BINA, 256, 0, stream>>>(src, dst, bucket_cursor, binned);
    bucket_scan_kernel<<<1, 256, 0, stream>>>(bucket_cursor, bucket_base, row_start);
    binB_sort_kernel<<<NBUCK, 1024, 0, stream>>>(binned, bucket_cursor, bucket_base,
                                                 row_start, src_sorted);

    // bf16 prep
    convert_x_kernel<<<NBLK_CV, 256, 0, stream>>>(x, xb);
    wprep1_kernel<<<(D * K2 + 255) / 256, 256, 0, stream>>>(Wl1, Wr1, Bt1);
    wprep2_kernel<<<(128 * 128 + 255) / 256, 256, 0, stream>>>(Wl2, Wr2, Bt2);

    // layer 1
    agg_mean_bf_kernel<<<NBLK_AGG, 256, 0, stream>>>(xb, row_start, src_sorted, meanb);
    linear1_mfma_kernel<<<NBLK_L, 512, 0, stream>>>(meanb, xb, Bt1, bl1, hpre, rn, csc);
    colreduce_kernel<<<1, 128, 0, stream>>>(csc, colmean);
    pairnorm_kernel<<<NBLK_CV, 256, 0, stream>>>(hpre, rn, colmean, hb);

    // layer 2: GEMM first, then fused aggregation (mean(h@Wl2) == mean(h)@Wl2)
    linear2_pre_kernel<<<NBLK_L, 512, 0, stream>>>(hb, Bt2, bl2, z, rbuf);
    agg2_fused_kernel<<<NBLK_AGG, 256, 0, stream>>>(z, rbuf, row_start, src_sorted, out);
}